// Round 3
// baseline (65.715 us; speedup 1.0000x reference)
//
#include <hip/hip_runtime.h>

// HQNN quanvolution, analytically collapsed (Heisenberg picture, DEPTH=1):
//   <Z0> = cos(w2)cos(w0)c0 - sin(w2)s0 s2
//   <Z1> = cos(w1)c1
//   <Z2> = cos(w0)c0 c2
//   <Z3> = cos(w3)<Z2>c3 - sin(w3)s3
// ck=cos(pi*pk), sk=sin(pi*pk); patch pixels p0=(i,j) p1=(i,j+1) p2=(i+1,j)
// p3=(i+1,j+1). Feature order for the linear head: f = q*729 + fi*27 + fj.
//
// R5: output-half pairing. Even lanes own outputs 0-4, odd lanes 5-9; each
// pair p=tid>>1 covers groups {p, p+256, p+512}. All 15 W float4s are
// prefetched at kernel entry -> removes the g1 (groups 512..728) cold HBM
// miss that R4 paid *inside* phase 2. Phase-3 partials halve (10 b32
// writes/thread, 256-wide rows, 16 serial reads). LDS 48.4 KB, 2 blocks/CU.

#define HD 28
#define NPIX 784          // 28*28
#define FD 27
#define NPATCH 729
#define NF 2916           // 4 * 729
#define NG 729            // float4 groups per W row
#define NOUT 10
#define IM 2              // images per block
#define NT 512            // threads per block
#define PSTR 264          // partials stride: 264 % 32 == 8 -> 2-way max (free)

__global__ __launch_bounds__(NT, 4)
void hqnn_fused(const float* __restrict__ x,
                const float* __restrict__ W,
                const float* __restrict__ bias,
                const float* __restrict__ wts,
                float* __restrict__ out)
{
    __shared__ __align__(16) float evl[IM][NF];
    __shared__ __align__(16) union U {
        struct { float sc[IM][NPIX]; float ss[IM][NPIX]; } tr;   // 25.1 KB
        float part[IM * NOUT][PSTR];                             // 21.1 KB
    } u;

    const int tid = threadIdx.x;
    const int p   = tid >> 1;          // pair id, 0..255
    const int h   = tid & 1;           // output half: 0 -> o=0..4, 1 -> o=5..9

    // ---- Phase 0: issue cold loads up front. x first (its waitcnt then
    // doesn't drain the W queue), then all 15 W rows for this thread's
    // 3 groups x 5 outputs. Every group 0..728 is covered at entry.
    const float4* xb4 = (const float4*)(x + (size_t)blockIdx.x * (IM * NPIX));
    const bool hasx = tid < (IM * NPIX / 4);   // 392 < NT
    float4 v;
    if (hasx) v = xb4[tid];

    const float4* W4 = (const float4*)W;
    const int g0 = p;
    const int g1 = p + 256;
    const bool has2 = (p < NG - 512);          // p < 217
    const int g2 = has2 ? p + 512 : 0;         // clamped (loaded, unused)
    float4 wr[3][5];
#pragma unroll
    for (int r = 0; r < 5; ++r) {
        const int row = (h * 5 + r) * NG;
        wr[0][r] = W4[row + g0];
        wr[1][r] = W4[row + g1];
        wr[2][r] = W4[row + g2];
    }

    // Circuit parameters (uniform; weights==0 at runtime -> cw=1, sw=0 exact).
    const float w0 = wts[0], w1 = wts[1], w2 = wts[2], w3 = wts[3];
    const float cw0 = cosf(w0);
    const float cw1 = cosf(w1);
    const float cw2 = cosf(w2), sw2 = sinf(w2);
    const float cw3 = cosf(w3), sw3 = sinf(w3);

    // ---- Phase 1: sincospi of both images into LDS (one float4 per thread).
    if (hasx) {
        const int p4  = tid * 4;
        const int img = (p4 >= NPIX) ? 1 : 0;   // IM == 2
        const int off = p4 - img * NPIX;
        float s0, c0, s1, c1, s2, c2, s3, c3;
        sincospif(v.x, &s0, &c0);
        sincospif(v.y, &s1, &c1);
        sincospif(v.z, &s2, &c2);
        sincospif(v.w, &s3, &c3);
        *(float4*)&u.tr.sc[img][off] = make_float4(c0, c1, c2, c3);
        *(float4*)&u.tr.ss[img][off] = make_float4(s0, s1, s2, s3);
    }
    __syncthreads();

    // ---- Phase 1.5: ev values, flat in feature order f = q*729 + patch.
    for (int pp = tid; pp < IM * NPATCH; pp += NT) {
        const int img = (pp >= NPATCH) ? 1 : 0;
        const int pa  = pp - img * NPATCH;
        const int fi  = pa / FD;
        const int fj  = pa - fi * FD;
        const int px  = fi * HD + fj;

        const float c00 = u.tr.sc[img][px];
        const float c01 = u.tr.sc[img][px + 1];
        const float c10 = u.tr.sc[img][px + HD];
        const float c11 = u.tr.sc[img][px + HD + 1];
        const float s00 = u.tr.ss[img][px];
        const float s10 = u.tr.ss[img][px + HD];
        const float s11 = u.tr.ss[img][px + HD + 1];

        const float ev2 = cw0 * c00 * c10;
        evl[img][pa]               = cw2 * cw0 * c00 - sw2 * s00 * s10;
        evl[img][NPATCH + pa]      = cw1 * c01;
        evl[img][2 * NPATCH + pa]  = ev2;
        evl[img][3 * NPATCH + pa]  = cw3 * ev2 * c11 - sw3 * s11;
    }
    __syncthreads();   // sc/ss dead from here; part may overlay them.

    // ---- Phase 2: each thread dots its 3 groups against its 5 W rows for
    // both images. All W already in registers; evl reads are LDS broadcasts
    // within each lane pair.
    const float4* e0 = (const float4*)evl[0];
    const float4* e1 = (const float4*)evl[1];
    float acc[IM][5];
#pragma unroll
    for (int m = 0; m < IM; ++m)
#pragma unroll
        for (int r = 0; r < 5; ++r) acc[m][r] = 0.f;

    {
        const float4 a = e0[g0];
        const float4 c = e1[g0];
#pragma unroll
        for (int r = 0; r < 5; ++r) {
            const float4 w = wr[0][r];
            acc[0][r] += a.x * w.x + a.y * w.y + a.z * w.z + a.w * w.w;
            acc[1][r] += c.x * w.x + c.y * w.y + c.z * w.z + c.w * w.w;
        }
    }
    {
        const float4 a = e0[g1];
        const float4 c = e1[g1];
#pragma unroll
        for (int r = 0; r < 5; ++r) {
            const float4 w = wr[1][r];
            acc[0][r] += a.x * w.x + a.y * w.y + a.z * w.z + a.w * w.w;
            acc[1][r] += c.x * w.x + c.y * w.y + c.z * w.z + c.w * w.w;
        }
    }
    if (has2) {
        const float4 a = e0[g2];
        const float4 c = e1[g2];
#pragma unroll
        for (int r = 0; r < 5; ++r) {
            const float4 w = wr[2][r];
            acc[0][r] += a.x * w.x + a.y * w.y + a.z * w.z + a.w * w.w;
            acc[1][r] += c.x * w.x + c.y * w.y + c.z * w.z + c.w * w.w;
        }
    }

    // ---- Phase 3: LDS partials (part overlays dead sc/ss). Row (m,o) is
    // written by the 256 threads of half h = o/5; 10 writes per thread.
    // Write banks: even/odd lanes hit disjoint-then-wrapping bank ranges,
    // 2-way max = free. Reader rows interleave at 8-bank offsets, 2-way max.
#pragma unroll
    for (int m = 0; m < IM; ++m)
#pragma unroll
        for (int r = 0; r < 5; ++r)
            u.part[m * NOUT + h * 5 + r][p] = acc[m][r];
    __syncthreads();

    if (tid < IM * NOUT * 16) {         // 320 lanes: 20 rows x 16 lanes
        const int row = tid >> 4;
        const int j   = tid & 15;
        float s = 0.f;
#pragma unroll
        for (int k = 0; k < 256; k += 16) s += u.part[row][j + k];
        s += __shfl_down(s, 8, 16);
        s += __shfl_down(s, 4, 16);
        s += __shfl_down(s, 2, 16);
        s += __shfl_down(s, 1, 16);
        if (j == 0) {
            const int img = (row >= NOUT) ? 1 : 0;
            const int o   = row - img * NOUT;
            out[(blockIdx.x * IM + img) * NOUT + o] = s + bias[o];
        }
    }
}

extern "C" void kernel_launch(void* const* d_in, const int* in_sizes, int n_in,
                              void* d_out, int out_size, void* d_ws, size_t ws_size,
                              hipStream_t stream) {
    const float* x    = (const float*)d_in[0];   // (B,1,28,28) f32
    const float* W    = (const float*)d_in[1];   // (10, 2916) f32
    const float* bias = (const float*)d_in[2];   // (10,) f32
    const float* wts  = (const float*)d_in[3];   // (1,4) f32 (zeros)
    float* out = (float*)d_out;                  // (B,10) f32

    const int B = in_sizes[0] / NPIX;            // 1024
    hqnn_fused<<<B / IM, NT, 0, stream>>>(x, W, bias, wts, out);
}

// Round 4
// 64.478 us; speedup vs baseline: 1.0192x; 1.0192x over previous
//
#include <hip/hip_runtime.h>

// HQNN quanvolution, analytically collapsed (Heisenberg picture, DEPTH=1):
//   <Z0> = cos(w2)cos(w0)c0 - sin(w2)s0 s2
//   <Z1> = cos(w1)c1
//   <Z2> = cos(w0)c0 c2
//   <Z3> = cos(w3)<Z2>c3 - sin(w3)s3
// ck=cos(pi*pk), sk=sin(pi*pk); patch pixels p0=(i,j) p1=(i,j+1) p2=(i+1,j)
// p3=(i+1,j+1). Feature order for the linear head: f = q*729 + fi*27 + fj.
//
// R6 = R4 restored (empirical best, 64.73 us). R5's full-W prefetch
// (60 VGPR live across phases 1/1.5 under a 128-reg cap, +1475 clamped
// loads/block) cost more than the g1 cold miss it removed (+1.0 us).
// Session accounting: poison fill ~40 us @ 83-85% HBM peak (untouchable)
// + launch overhead + ~4-8 us kernel; structural deltas are in the
// +-0.5-1 us noise band -> this is the harness floor.
//
// R4: 512-thread blocks (16 waves/CU), entry prefetch of x + 10 g0 W-rows,
// phase 3 via LDS partials part[20][520] overlaid on dead sc/ss (union),
// stride 520 = 8 (mod 32) -> conflict-free. LDS 64.9 KB -> 2 blocks/CU.

#define HD 28
#define NPIX 784          // 28*28
#define FD 27
#define NPATCH 729
#define NF 2916           // 4 * 729
#define NG 729            // float4 groups per W row
#define NOUT 10
#define IM 2              // images per block
#define NT 512            // threads per block
#define PSTR 520          // partials stride: 520 % 32 == 8 -> conflict-free read

__global__ __launch_bounds__(NT, 4)
void hqnn_fused(const float* __restrict__ x,
                const float* __restrict__ W,
                const float* __restrict__ bias,
                const float* __restrict__ wts,
                float* __restrict__ out)
{
    __shared__ __align__(16) float evl[IM][NF];
    __shared__ __align__(16) union U {
        struct { float sc[IM][NPIX]; float ss[IM][NPIX]; } tr;   // 25.1 KB
        float part[IM * NOUT][PSTR];                             // 41.6 KB
    } u;

    const int tid = threadIdx.x;

    // ---- Phase 0: issue the cold loads up front. x first (its waitcnt then
    // doesn't have to drain the W prefetch queue), then 10 W rows for g0.
    const float4* xb4 = (const float4*)(x + (size_t)blockIdx.x * (IM * NPIX));
    const bool hasx = tid < (IM * NPIX / 4);   // 392 < NT
    float4 v;
    if (hasx) v = xb4[tid];

    const float4* W4 = (const float4*)W;
    const int g0 = tid;                        // always < NG (512 < 729)
    float4 wA[NOUT];
#pragma unroll
    for (int o = 0; o < NOUT; ++o) wA[o] = W4[o * NG + g0];

    // Circuit parameters (uniform; weights==0 at runtime -> cw=1, sw=0 exact).
    const float w0 = wts[0], w1 = wts[1], w2 = wts[2], w3 = wts[3];
    const float cw0 = cosf(w0);
    const float cw1 = cosf(w1);
    const float cw2 = cosf(w2), sw2 = sinf(w2);
    const float cw3 = cosf(w3), sw3 = sinf(w3);

    // ---- Phase 1: sincospi of both images into LDS (one float4 per thread).
    if (hasx) {
        const int p4  = tid * 4;
        const int img = (p4 >= NPIX) ? 1 : 0;   // IM == 2
        const int off = p4 - img * NPIX;
        float s0, c0, s1, c1, s2, c2, s3, c3;
        sincospif(v.x, &s0, &c0);
        sincospif(v.y, &s1, &c1);
        sincospif(v.z, &s2, &c2);
        sincospif(v.w, &s3, &c3);
        *(float4*)&u.tr.sc[img][off] = make_float4(c0, c1, c2, c3);
        *(float4*)&u.tr.ss[img][off] = make_float4(s0, s1, s2, s3);
    }
    __syncthreads();

    // ---- Phase 1.5: ev values, flat in feature order f = q*729 + patch.
    for (int pp = tid; pp < IM * NPATCH; pp += NT) {
        const int img = (pp >= NPATCH) ? 1 : 0;
        const int pa  = pp - img * NPATCH;
        const int fi  = pa / FD;
        const int fj  = pa - fi * FD;
        const int p   = fi * HD + fj;

        const float c00 = u.tr.sc[img][p];
        const float c01 = u.tr.sc[img][p + 1];
        const float c10 = u.tr.sc[img][p + HD];
        const float c11 = u.tr.sc[img][p + HD + 1];
        const float s00 = u.tr.ss[img][p];
        const float s10 = u.tr.ss[img][p + HD];
        const float s11 = u.tr.ss[img][p + HD + 1];

        const float ev2 = cw0 * c00 * c10;
        evl[img][pa]               = cw2 * cw0 * c00 - sw2 * s00 * s10;
        evl[img][NPATCH + pa]      = cw1 * c01;
        evl[img][2 * NPATCH + pa]  = ev2;
        evl[img][3 * NPATCH + pa]  = cw3 * ev2 * c11 - sw3 * s11;
    }
    __syncthreads();   // sc/ss dead from here; part may overlay them.

    // ---- Phase 2: aligned float4 dots. g0 uses the prefetched W rows;
    // only tids < 217 have a second group g1.
    const float4* e0 = (const float4*)evl[0];
    const float4* e1 = (const float4*)evl[1];
    float acc[IM][NOUT];
    {
        const float4 a = e0[g0];
        const float4 c = e1[g0];
#pragma unroll
        for (int o = 0; o < NOUT; ++o) {
            const float4 w = wA[o];
            acc[0][o] = a.x * w.x + a.y * w.y + a.z * w.z + a.w * w.w;
            acc[1][o] = c.x * w.x + c.y * w.y + c.z * w.z + c.w * w.w;
        }
    }
    const int g1 = tid + NT;
    if (g1 < NG) {
        const float4 a = e0[g1];
        const float4 c = e1[g1];
#pragma unroll
        for (int o = 0; o < NOUT; ++o) {
            const float4 w = W4[o * NG + g1];
            acc[0][o] += a.x * w.x + a.y * w.y + a.z * w.z + a.w * w.w;
            acc[1][o] += c.x * w.x + c.y * w.y + c.z * w.z + c.w * w.w;
        }
    }

    // ---- Phase 3: LDS partial reduction (part overlays sc/ss).
#pragma unroll
    for (int m = 0; m < IM; ++m)
#pragma unroll
        for (int o = 0; o < NOUT; ++o) u.part[m * NOUT + o][tid] = acc[m][o];
    __syncthreads();

    if (tid < IM * NOUT * 16) {         // 320 lanes: 20 rows x 16 lanes
        const int row = tid >> 4;
        const int j   = tid & 15;
        float s = 0.f;
#pragma unroll
        for (int k = 0; k < NT; k += 16) s += u.part[row][j + k];
        s += __shfl_down(s, 8, 16);
        s += __shfl_down(s, 4, 16);
        s += __shfl_down(s, 2, 16);
        s += __shfl_down(s, 1, 16);
        if (j == 0) {
            const int img = (row >= NOUT) ? 1 : 0;
            const int o   = row - img * NOUT;
            out[(blockIdx.x * IM + img) * NOUT + o] = s + bias[o];
        }
    }
}

extern "C" void kernel_launch(void* const* d_in, const int* in_sizes, int n_in,
                              void* d_out, int out_size, void* d_ws, size_t ws_size,
                              hipStream_t stream) {
    const float* x    = (const float*)d_in[0];   // (B,1,28,28) f32
    const float* W    = (const float*)d_in[1];   // (10, 2916) f32
    const float* bias = (const float*)d_in[2];   // (10,) f32
    const float* wts  = (const float*)d_in[3];   // (1,4) f32 (zeros)
    float* out = (float*)d_out;                  // (B,10) f32

    const int B = in_sizes[0] / NPIX;            // 1024
    hqnn_fused<<<B / IM, NT, 0, stream>>>(x, W, bias, wts, out);
}